// Round 7
// baseline (303.328 us; speedup 1.0000x reference)
//
#include <hip/hip_runtime.h>
#include <math.h>

#define NN 2048
#define BATCH 8
#define FDIM 128

// ---------------- kernel 1: positional encoding table pe[2048][128] --------
__global__ void k_pe(float* __restrict__ pe) {
    int i = blockIdx.x * 256 + threadIdx.x;       // 0 .. 2048*128-1
    int n = i >> 7;
    int k = i & 127;
    int jj = k >> 1;
    float dt = expf((float)(2 * jj) * (-0.07195578415606394f)); // -ln(1e4)/128
    float ang = (float)n * dt;
    float decay = 1.f + expf(-(float)n * 0.01f);
    float v = ((k & 1) == 0 ? sinf(ang) : cosf(ang)) * decay;
    pe[i] = v;
}

// ---------------- kernel 2: Wh = (h+pe) @ W ; s1 = Wh@a1 ; s2 = Wh@a2 ------
__global__ __launch_bounds__(512) void k_wh(const float* __restrict__ h,
                                            const float* __restrict__ pe,
                                            const float* __restrict__ W,
                                            const float* __restrict__ a,
                                            float* __restrict__ Wh,
                                            float* __restrict__ s1,
                                            float* __restrict__ s2) {
    __shared__ float w_lds[64 * 128];     // 32 KB: W[kp*64 + k][c]
    __shared__ float hpe_lds[64 * 68];    // 17.4 KB: rows 64, stride 68 (bank pad)
    const int b  = blockIdx.y;
    const int n0 = blockIdx.x * 64;
    const int t  = threadIdx.x;
    const int tc = t & 15;                // col group -> cols tc*8..+7
    const int tr = t >> 4;                // row group 0..31 -> rows tr*2..+1

    float acc[2][8];
#pragma unroll
    for (int i = 0; i < 2; i++)
#pragma unroll
        for (int j = 0; j < 8; j++) acc[i][j] = 0.f;

    for (int kp = 0; kp < 2; ++kp) {
        {   // load W half: 2048 float4 by 512 threads
            const float4* wsrc = (const float4*)(W + kp * 64 * 128);
            float4* wdst = (float4*)w_lds;
#pragma unroll
            for (int q = 0; q < 4; q++) wdst[t + q * 512] = wsrc[t + q * 512];
        }
        {   // load hpe tile: 1024 float4 by 512 threads
#pragma unroll
            for (int q = 0; q < 2; q++) {
                int f = t + q * 512;          // float4 index 0..1023
                int r = f >> 4;               // row 0..63
                int k4 = (f & 15) << 2;       // k offset 0..60
                int n = n0 + r;
                int kk = kp * 64 + k4;
                float4 hv = *(const float4*)(h + ((size_t)b * NN + n) * FDIM + kk);
                float4 pv = *(const float4*)(pe + (size_t)n * FDIM + kk);
                *(float4*)(hpe_lds + r * 68 + k4) =
                    make_float4(hv.x + pv.x, hv.y + pv.y, hv.z + pv.z, hv.w + pv.w);
            }
        }
        __syncthreads();
#pragma unroll 4
        for (int k = 0; k < 64; k++) {
            float wv[8];
            float4 wa = *(float4*)(w_lds + k * 128 + tc * 8);
            float4 wb = *(float4*)(w_lds + k * 128 + tc * 8 + 4);
            wv[0] = wa.x; wv[1] = wa.y; wv[2] = wa.z; wv[3] = wa.w;
            wv[4] = wb.x; wv[5] = wb.y; wv[6] = wb.z; wv[7] = wb.w;
#pragma unroll
            for (int i = 0; i < 2; i++) {
                float hv = hpe_lds[(tr * 2 + i) * 68 + k];
#pragma unroll
                for (int j = 0; j < 8; j++) acc[i][j] = fmaf(hv, wv[j], acc[i][j]);
            }
        }
        __syncthreads();
    }

    float a1v[8], a2v[8];
#pragma unroll
    for (int j = 0; j < 8; j++) { a1v[j] = a[tc * 8 + j]; a2v[j] = a[FDIM + tc * 8 + j]; }
#pragma unroll
    for (int i = 0; i < 2; i++) {
        int n = n0 + tr * 2 + i;
        float* dst = Wh + ((size_t)b * NN + n) * FDIM + tc * 8;
        *(float4*)dst = make_float4(acc[i][0], acc[i][1], acc[i][2], acc[i][3]);
        *(float4*)(dst + 4) = make_float4(acc[i][4], acc[i][5], acc[i][6], acc[i][7]);
        float p1 = 0.f, p2 = 0.f;
#pragma unroll
        for (int j = 0; j < 8; j++) {
            p1 = fmaf(acc[i][j], a1v[j], p1);
            p2 = fmaf(acc[i][j], a2v[j], p2);
        }
#pragma unroll
        for (int off = 1; off < 16; off <<= 1) {   // reduce across the 16 tc lanes
            p1 += __shfl_xor(p1, off, 64);
            p2 += __shfl_xor(p2, off, 64);
        }
        if (tc == 0) {
            s1[(size_t)b * NN + n] = p1;
            s2[(size_t)b * NN + n] = p2;
        }
    }
}

// ---------------- kernel 3: stream adj, row softmax, column-sum partials ---
// grid (256 chunks of 8 rows, 8 b) = 2048 blocks, 256 threads = 4 waves.
// Each wave processes a ROW PAIR concurrently: 16 independent float4 loads
// in flight, independent exp/zsum chains, interleaved reduces. p kept in
// registers (no exp recompute). s2 in LDS (saves 32 VGPRs).
__global__ __launch_bounds__(256) void k_attn(const float* __restrict__ adj,
                                              const float* __restrict__ s1,
                                              const float* __restrict__ s2,
                                              float* __restrict__ c_part) {
    const int b = blockIdx.y;
    const int chunk = blockIdx.x;      // 8 rows per chunk
    const int t = threadIdx.x;
    const int wave = t >> 6;
    const int lane = t & 63;
    __shared__ float c_lds[NN];        // 8 KB
    __shared__ float s2_lds[NN];       // 8 KB
    const float* s2b = s2 + (size_t)b * NN;
    for (int i = t; i < NN; i += 256) c_lds[i] = 0.f;
#pragma unroll
    for (int q = 0; q < 2; q++) {
        int idx = t + q * 256;
        ((float4*)s2_lds)[idx] = ((const float4*)s2b)[idx];
    }
    __syncthreads();

    const int na = chunk * 8 + wave * 2;
    const int nb_ = na + 1;
    const float* adjb = adj + (size_t)b * NN * NN;
    const float* s1b = s1 + (size_t)b * NN;
    const float s1A = s1b[na];
    const float s1B = s1b[nb_];
    const float4* rowA = (const float4*)(adjb + (size_t)na * NN);
    const float4* rowB = (const float4*)(adjb + (size_t)nb_ * NN);

    // issue all 16 loads (compiler schedules them together: max MLP)
    float4 avA[8], avB[8];
#pragma unroll
    for (int kq = 0; kq < 8; kq++) avA[kq] = rowA[kq * 64 + lane];
#pragma unroll
    for (int kq = 0; kq < 8; kq++) avB[kq] = rowB[kq * 64 + lane];

    float pA[32], pB[32];
    float zA = 0.f, zB = 0.f;
#pragma unroll
    for (int kq = 0; kq < 8; kq++) {
        float4 sv = ((const float4*)s2_lds)[kq * 64 + lane];
        float sv4[4] = {sv.x, sv.y, sv.z, sv.w};
        float aA[4] = {avA[kq].x, avA[kq].y, avA[kq].z, avA[kq].w};
        float aB[4] = {avB[kq].x, avB[kq].y, avB[kq].z, avB[kq].w};
#pragma unroll
        for (int e = 0; e < 4; e++) {
            int j = kq * 4 + e;
            int m = kq * 256 + lane * 4 + e;
            float xA = s1A + sv4[e];
            float evA = fmaxf(xA, 0.2f * xA);                // LeakyReLU
            float vA = ((aA[e] > 0.f) || (m == na)) ? __expf(evA) : 0.f;
            pA[j] = vA; zA += vA;
            float xB = s1B + sv4[e];
            float evB = fmaxf(xB, 0.2f * xB);
            float vB = ((aB[e] > 0.f) || (m == nb_)) ? __expf(evB) : 0.f;
            pB[j] = vB; zB += vB;
        }
    }
#pragma unroll
    for (int off = 32; off; off >>= 1) {
        zA += __shfl_xor(zA, off, 64);
        zB += __shfl_xor(zB, off, 64);
    }
    const float rzA = (na != 0) ? 1.f / zA : 0.f;  // row 0 excluded (valid[:,0]=False)
    const float rzB = 1.f / zB;

#pragma unroll
    for (int kq = 0; kq < 8; kq++)
#pragma unroll
        for (int e = 0; e < 4; e++) {
            int j = kq * 4 + e;
            int m = kq * 256 + lane * 4 + e;
            atomicAdd(&c_lds[m], pA[j] * rzA + pB[j] * rzB);
        }
    __syncthreads();

    float* dst = c_part + ((size_t)b * 256 + chunk) * NN;
#pragma unroll
    for (int q = 0; q < 2; q++) {
        int idx = t + q * 256;   // float4 index 0..511
        ((float4*)dst)[idx] = ((const float4*)c_lds)[idx];
    }
}

// ---------------- kernel 4: reduce c_part + g_part = c^T * Wh partials -----
// grid (32 m-chunks of 64, 8 b), 256 threads
__global__ __launch_bounds__(256) void k_gpre(const float* __restrict__ Wh,
                                              const float* __restrict__ c_part,
                                              float* __restrict__ g_part) {
    const int b = blockIdx.y;
    const int mc = blockIdx.x;
    const int m0 = mc * 64;
    const int t = threadIdx.x;
    __shared__ float red[256];
    __shared__ float c_lds[64];

    // phase 1: c[b][m0+mi] = sum over 256 chunk-partials (4 waves x 64 each)
    {
        const int mi = t & 63;
        const int w = t >> 6;
        const float* cp = c_part + (size_t)b * 256 * NN + m0 + mi;
        float s = 0.f;
#pragma unroll 8
        for (int j = 0; j < 64; j++) s += cp[(size_t)(w * 64 + j) * NN];
        red[w * 64 + mi] = s;
    }
    __syncthreads();
    if (t < 64) c_lds[t] = red[t] + red[t + 64] + red[t + 128] + red[t + 192];
    __syncthreads();

    // phase 2: partial g over this m-chunk
    const int o = t & 127;
    const int mh = t >> 7;              // 0/1
    float acc = 0.f;
    const float* whb = Wh + ((size_t)b * NN + m0 + mh * 32) * FDIM;
#pragma unroll 4
    for (int mm = 0; mm < 32; mm++)
        acc = fmaf(c_lds[mh * 32 + mm], whb[mm * FDIM + o], acc);
    g_part[((size_t)(mc * 2 + mh)) * (BATCH * FDIM) + b * FDIM + o] = acc;
}

// ---------------- kernel 5: out = elu( (sum of 64 partials) / 2047 ) -------
__global__ void k_elu(const float* __restrict__ g_part, float* __restrict__ out) {
    int i = blockIdx.x * 256 + threadIdx.x;    // 0..1023 = b*128+o
    if (i < BATCH * FDIM) {
        float s = 0.f;
#pragma unroll 8
        for (int p = 0; p < 64; p++) s += g_part[p * (BATCH * FDIM) + i];
        float g = s * (1.0f / 2047.0f);
        out[i] = g > 0.f ? g : expm1f(g);
    }
}

extern "C" void kernel_launch(void* const* d_in, const int* in_sizes, int n_in,
                              void* d_out, int out_size, void* d_ws, size_t ws_size,
                              hipStream_t stream) {
    (void)in_sizes; (void)n_in; (void)out_size; (void)ws_size;
    const float* h   = (const float*)d_in[0];
    const float* adj = (const float*)d_in[1];
    const float* W   = (const float*)d_in[2];
    const float* a   = (const float*)d_in[3];
    float* out = (float*)d_out;

    char* ws = (char*)d_ws;
    float* Wh     = (float*)ws;                                   // 8*2048*128
    float* pe     = Wh + (size_t)BATCH * NN * FDIM;               // 2048*128
    float* s1     = pe + (size_t)NN * FDIM;                       // 8*2048
    float* s2     = s1 + (size_t)BATCH * NN;                      // 8*2048
    float* c_part = s2 + (size_t)BATCH * NN;                      // 8*256*2048
    float* g_part = c_part + (size_t)BATCH * 256 * NN;            // 64*8*128

    hipLaunchKernelGGL(k_pe, dim3(NN * FDIM / 256), dim3(256), 0, stream, pe);
    hipLaunchKernelGGL(k_wh, dim3(NN / 64, BATCH), dim3(512), 0, stream,
                       h, pe, W, a, Wh, s1, s2);
    hipLaunchKernelGGL(k_attn, dim3(NN / 8, BATCH), dim3(256), 0, stream,
                       adj, s1, s2, c_part);
    hipLaunchKernelGGL(k_gpre, dim3(NN / 64, BATCH), dim3(256), 0, stream,
                       Wh, c_part, g_part);
    hipLaunchKernelGGL(k_elu, dim3(4), dim3(256), 0, stream, g_part, out);
}

// Round 9
// 295.601 us; speedup vs baseline: 1.0261x; 1.0261x over previous
//
#include <hip/hip_runtime.h>
#include <math.h>

#define NN 2048
#define BATCH 8
#define FDIM 128

// ---------------- kernel 1: positional encoding table pe[2048][128] --------
__global__ void k_pe(float* __restrict__ pe) {
    int i = blockIdx.x * 256 + threadIdx.x;       // 0 .. 2048*128-1
    int n = i >> 7;
    int k = i & 127;
    int jj = k >> 1;
    float dt = expf((float)(2 * jj) * (-0.07195578415606394f)); // -ln(1e4)/128
    float ang = (float)n * dt;
    float decay = 1.f + expf(-(float)n * 0.01f);
    float v = ((k & 1) == 0 ? sinf(ang) : cosf(ang)) * decay;
    pe[i] = v;
}

// ---------------- kernel 2: Wh = (h+pe) @ W ; s1 = Wh@a1 ; s2 = Wh@a2 ------
__global__ __launch_bounds__(512) void k_wh(const float* __restrict__ h,
                                            const float* __restrict__ pe,
                                            const float* __restrict__ W,
                                            const float* __restrict__ a,
                                            float* __restrict__ Wh,
                                            float* __restrict__ s1,
                                            float* __restrict__ s2) {
    __shared__ float w_lds[64 * 128];     // 32 KB: W[kp*64 + k][c]
    __shared__ float hpe_lds[64 * 68];    // 17.4 KB: rows 64, stride 68 (bank pad)
    const int b  = blockIdx.y;
    const int n0 = blockIdx.x * 64;
    const int t  = threadIdx.x;
    const int tc = t & 15;                // col group -> cols tc*8..+7
    const int tr = t >> 4;                // row group 0..31 -> rows tr*2..+1

    float acc[2][8];
#pragma unroll
    for (int i = 0; i < 2; i++)
#pragma unroll
        for (int j = 0; j < 8; j++) acc[i][j] = 0.f;

    for (int kp = 0; kp < 2; ++kp) {
        {   // load W half: 2048 float4 by 512 threads
            const float4* wsrc = (const float4*)(W + kp * 64 * 128);
            float4* wdst = (float4*)w_lds;
#pragma unroll
            for (int q = 0; q < 4; q++) wdst[t + q * 512] = wsrc[t + q * 512];
        }
        {   // load hpe tile: 1024 float4 by 512 threads
#pragma unroll
            for (int q = 0; q < 2; q++) {
                int f = t + q * 512;          // float4 index 0..1023
                int r = f >> 4;               // row 0..63
                int k4 = (f & 15) << 2;       // k offset 0..60
                int n = n0 + r;
                int kk = kp * 64 + k4;
                float4 hv = *(const float4*)(h + ((size_t)b * NN + n) * FDIM + kk);
                float4 pv = *(const float4*)(pe + (size_t)n * FDIM + kk);
                *(float4*)(hpe_lds + r * 68 + k4) =
                    make_float4(hv.x + pv.x, hv.y + pv.y, hv.z + pv.z, hv.w + pv.w);
            }
        }
        __syncthreads();
#pragma unroll 4
        for (int k = 0; k < 64; k++) {
            float wv[8];
            float4 wa = *(float4*)(w_lds + k * 128 + tc * 8);
            float4 wb = *(float4*)(w_lds + k * 128 + tc * 8 + 4);
            wv[0] = wa.x; wv[1] = wa.y; wv[2] = wa.z; wv[3] = wa.w;
            wv[4] = wb.x; wv[5] = wb.y; wv[6] = wb.z; wv[7] = wb.w;
#pragma unroll
            for (int i = 0; i < 2; i++) {
                float hv = hpe_lds[(tr * 2 + i) * 68 + k];
#pragma unroll
                for (int j = 0; j < 8; j++) acc[i][j] = fmaf(hv, wv[j], acc[i][j]);
            }
        }
        __syncthreads();
    }

    float a1v[8], a2v[8];
#pragma unroll
    for (int j = 0; j < 8; j++) { a1v[j] = a[tc * 8 + j]; a2v[j] = a[FDIM + tc * 8 + j]; }
#pragma unroll
    for (int i = 0; i < 2; i++) {
        int n = n0 + tr * 2 + i;
        float* dst = Wh + ((size_t)b * NN + n) * FDIM + tc * 8;
        *(float4*)dst = make_float4(acc[i][0], acc[i][1], acc[i][2], acc[i][3]);
        *(float4*)(dst + 4) = make_float4(acc[i][4], acc[i][5], acc[i][6], acc[i][7]);
        float p1 = 0.f, p2 = 0.f;
#pragma unroll
        for (int j = 0; j < 8; j++) {
            p1 = fmaf(acc[i][j], a1v[j], p1);
            p2 = fmaf(acc[i][j], a2v[j], p2);
        }
#pragma unroll
        for (int off = 1; off < 16; off <<= 1) {   // reduce across the 16 tc lanes
            p1 += __shfl_xor(p1, off, 64);
            p2 += __shfl_xor(p2, off, 64);
        }
        if (tc == 0) {
            s1[(size_t)b * NN + n] = p1;
            s2[(size_t)b * NN + n] = p2;
        }
    }
}

// ---------------- kernel 3: stream adj, row softmax, column-sum partials ---
// grid (256 chunks of 8 rows, 8 b) = 2048 blocks, 256 threads = 4 waves.
// Row PAIR per wave, kq-interleaved (2 global + 1 LDS load per step).
// NO p-array storage (avoids r7's scratch spill): conn bitmask + exp
// recompute in the normalize pass. Batched cross-lane reduces.
__global__ __launch_bounds__(256) void k_attn(const float* __restrict__ adj,
                                              const float* __restrict__ s1,
                                              const float* __restrict__ s2,
                                              float* __restrict__ c_part) {
    const int b = blockIdx.y;
    const int chunk = blockIdx.x;      // 8 rows per chunk
    const int t = threadIdx.x;
    const int wave = t >> 6;
    const int lane = t & 63;
    __shared__ float c_lds[NN];        // 8 KB
    __shared__ float s2_lds[NN];       // 8 KB
    const float* s2b = s2 + (size_t)b * NN;
    for (int i = t; i < NN; i += 256) c_lds[i] = 0.f;
#pragma unroll
    for (int q = 0; q < 2; q++) {
        int idx = t + q * 256;
        ((float4*)s2_lds)[idx] = ((const float4*)s2b)[idx];
    }
    __syncthreads();

    const int na = chunk * 8 + wave * 2;
    const int nb_ = na + 1;
    const float* adjb = adj + (size_t)b * NN * NN;
    const float* s1b = s1 + (size_t)b * NN;
    const float s1A = s1b[na];
    const float s1B = s1b[nb_];
    const float4* rowA = (const float4*)(adjb + (size_t)na * NN);
    const float4* rowB = (const float4*)(adjb + (size_t)nb_ * NN);

    // pass 1: connectivity masks + partial zsums (no p storage -> no spill)
    unsigned mkA = 0u, mkB = 0u;
    float zA = 0.f, zB = 0.f;
#pragma unroll
    for (int kq = 0; kq < 8; kq++) {
        float4 avA = rowA[kq * 64 + lane];
        float4 avB = rowB[kq * 64 + lane];
        float4 sv = ((const float4*)s2_lds)[kq * 64 + lane];
        float sv4[4] = {sv.x, sv.y, sv.z, sv.w};
        float aA[4] = {avA.x, avA.y, avA.z, avA.w};
        float aB[4] = {avB.x, avB.y, avB.z, avB.w};
#pragma unroll
        for (int e = 0; e < 4; e++) {
            int j = kq * 4 + e;
            int m = kq * 256 + lane * 4 + e;
            float xA = s1A + sv4[e];
            float evA = fmaxf(xA, 0.2f * xA);            // LeakyReLU
            bool cA = (aA[e] > 0.f) || (m == na);        // forced diagonal
            mkA |= (unsigned)cA << j;
            zA += cA ? __expf(evA) : 0.f;
            float xB = s1B + sv4[e];
            float evB = fmaxf(xB, 0.2f * xB);
            bool cB = (aB[e] > 0.f) || (m == nb_);
            mkB |= (unsigned)cB << j;
            zB += cB ? __expf(evB) : 0.f;
        }
    }
    // batched (pipelined) cross-lane reduces
#pragma unroll
    for (int off = 32; off; off >>= 1) {
        zA += __shfl_xor(zA, off, 64);
        zB += __shfl_xor(zB, off, 64);
    }
    const float rzA = (na != 0) ? 1.f / zA : 0.f;  // row 0 excluded (valid[:,0]=False)
    const float rzB = 1.f / zB;

    // pass 2: recompute exp, normalize, accumulate into LDS via atomics
#pragma unroll
    for (int kq = 0; kq < 8; kq++) {
        float4 sv = ((const float4*)s2_lds)[kq * 64 + lane];
        float sv4[4] = {sv.x, sv.y, sv.z, sv.w};
#pragma unroll
        for (int e = 0; e < 4; e++) {
            int j = kq * 4 + e;
            int m = kq * 256 + lane * 4 + e;
            float xA = s1A + sv4[e];
            float pA = ((mkA >> j) & 1u) ? __expf(fmaxf(xA, 0.2f * xA)) : 0.f;
            float xB = s1B + sv4[e];
            float pB = ((mkB >> j) & 1u) ? __expf(fmaxf(xB, 0.2f * xB)) : 0.f;
            atomicAdd(&c_lds[m], pA * rzA + pB * rzB);
        }
    }
    __syncthreads();

    float* dst = c_part + ((size_t)b * 256 + chunk) * NN;
#pragma unroll
    for (int q = 0; q < 2; q++) {
        int idx = t + q * 256;   // float4 index 0..511
        ((float4*)dst)[idx] = ((const float4*)c_lds)[idx];
    }
}

// ---------------- kernel 4: reduce c_part + g_part = c^T * Wh partials -----
// grid (32 m-chunks of 64, 8 b), 256 threads
__global__ __launch_bounds__(256) void k_gpre(const float* __restrict__ Wh,
                                              const float* __restrict__ c_part,
                                              float* __restrict__ g_part) {
    const int b = blockIdx.y;
    const int mc = blockIdx.x;
    const int m0 = mc * 64;
    const int t = threadIdx.x;
    __shared__ float red[256];
    __shared__ float c_lds[64];

    // phase 1: c[b][m0+mi] = sum over 256 chunk-partials (4 waves x 64 each)
    {
        const int mi = t & 63;
        const int w = t >> 6;
        const float* cp = c_part + (size_t)b * 256 * NN + m0 + mi;
        float s = 0.f;
#pragma unroll 8
        for (int j = 0; j < 64; j++) s += cp[(size_t)(w * 64 + j) * NN];
        red[w * 64 + mi] = s;
    }
    __syncthreads();
    if (t < 64) c_lds[t] = red[t] + red[t + 64] + red[t + 128] + red[t + 192];
    __syncthreads();

    // phase 2: partial g over this m-chunk
    const int o = t & 127;
    const int mh = t >> 7;              // 0/1
    float acc = 0.f;
    const float* whb = Wh + ((size_t)b * NN + m0 + mh * 32) * FDIM;
#pragma unroll 4
    for (int mm = 0; mm < 32; mm++)
        acc = fmaf(c_lds[mh * 32 + mm], whb[mm * FDIM + o], acc);
    g_part[((size_t)(mc * 2 + mh)) * (BATCH * FDIM) + b * FDIM + o] = acc;
}

// ---------------- kernel 5: out = elu( (sum of 64 partials) / 2047 ) -------
__global__ void k_elu(const float* __restrict__ g_part, float* __restrict__ out) {
    int i = blockIdx.x * 256 + threadIdx.x;    // 0..1023 = b*128+o
    if (i < BATCH * FDIM) {
        float s = 0.f;
#pragma unroll 8
        for (int p = 0; p < 64; p++) s += g_part[p * (BATCH * FDIM) + i];
        float g = s * (1.0f / 2047.0f);
        out[i] = g > 0.f ? g : expm1f(g);
    }
}

extern "C" void kernel_launch(void* const* d_in, const int* in_sizes, int n_in,
                              void* d_out, int out_size, void* d_ws, size_t ws_size,
                              hipStream_t stream) {
    (void)in_sizes; (void)n_in; (void)out_size; (void)ws_size;
    const float* h   = (const float*)d_in[0];
    const float* adj = (const float*)d_in[1];
    const float* W   = (const float*)d_in[2];
    const float* a   = (const float*)d_in[3];
    float* out = (float*)d_out;

    char* ws = (char*)d_ws;
    float* Wh     = (float*)ws;                                   // 8*2048*128
    float* pe     = Wh + (size_t)BATCH * NN * FDIM;               // 2048*128
    float* s1     = pe + (size_t)NN * FDIM;                       // 8*2048
    float* s2     = s1 + (size_t)BATCH * NN;                      // 8*2048
    float* c_part = s2 + (size_t)BATCH * NN;                      // 8*256*2048
    float* g_part = c_part + (size_t)BATCH * 256 * NN;            // 64*8*128

    hipLaunchKernelGGL(k_pe, dim3(NN * FDIM / 256), dim3(256), 0, stream, pe);
    hipLaunchKernelGGL(k_wh, dim3(NN / 64, BATCH), dim3(512), 0, stream,
                       h, pe, W, a, Wh, s1, s2);
    hipLaunchKernelGGL(k_attn, dim3(NN / 8, BATCH), dim3(256), 0, stream,
                       adj, s1, s2, c_part);
    hipLaunchKernelGGL(k_gpre, dim3(NN / 64, BATCH), dim3(256), 0, stream,
                       Wh, c_part, g_part);
    hipLaunchKernelGGL(k_elu, dim3(4), dim3(256), 0, stream, g_part, out);
}

// Round 13
// 222.705 us; speedup vs baseline: 1.3620x; 1.3273x over previous
//
#include <hip/hip_runtime.h>
#include <math.h>

#define NN 2048
#define BATCH 8
#define FDIM 128

// ---------------- kernel 1: positional encoding table pe[2048][128] --------
__global__ void k_pe(float* __restrict__ pe) {
    int i = blockIdx.x * 256 + threadIdx.x;       // 0 .. 2048*128-1
    int n = i >> 7;
    int k = i & 127;
    int jj = k >> 1;
    float dt = expf((float)(2 * jj) * (-0.07195578415606394f)); // -ln(1e4)/128
    float ang = (float)n * dt;
    float decay = 1.f + expf(-(float)n * 0.01f);
    float v = ((k & 1) == 0 ? sinf(ang) : cosf(ang)) * decay;
    pe[i] = v;
}

// ---------------- kernel 2: Wh = (h+pe) @ W ; s1 = Wh@a1 ; s2 = Wh@a2 ------
__global__ __launch_bounds__(512) void k_wh(const float* __restrict__ h,
                                            const float* __restrict__ pe,
                                            const float* __restrict__ W,
                                            const float* __restrict__ a,
                                            float* __restrict__ Wh,
                                            float* __restrict__ s1,
                                            float* __restrict__ s2) {
    __shared__ float w_lds[64 * 128];     // 32 KB: W[kp*64 + k][c]
    __shared__ float hpe_lds[64 * 68];    // 17.4 KB: rows 64, stride 68 (bank pad)
    const int b  = blockIdx.y;
    const int n0 = blockIdx.x * 64;
    const int t  = threadIdx.x;
    const int tc = t & 15;                // col group -> cols tc*8..+7
    const int tr = t >> 4;                // row group 0..31 -> rows tr*2..+1

    float acc[2][8];
#pragma unroll
    for (int i = 0; i < 2; i++)
#pragma unroll
        for (int j = 0; j < 8; j++) acc[i][j] = 0.f;

    for (int kp = 0; kp < 2; ++kp) {
        {   // load W half: 2048 float4 by 512 threads
            const float4* wsrc = (const float4*)(W + kp * 64 * 128);
            float4* wdst = (float4*)w_lds;
#pragma unroll
            for (int q = 0; q < 4; q++) wdst[t + q * 512] = wsrc[t + q * 512];
        }
        {   // load hpe tile: 1024 float4 by 512 threads
#pragma unroll
            for (int q = 0; q < 2; q++) {
                int f = t + q * 512;          // float4 index 0..1023
                int r = f >> 4;               // row 0..63
                int k4 = (f & 15) << 2;       // k offset 0..60
                int n = n0 + r;
                int kk = kp * 64 + k4;
                float4 hv = *(const float4*)(h + ((size_t)b * NN + n) * FDIM + kk);
                float4 pv = *(const float4*)(pe + (size_t)n * FDIM + kk);
                *(float4*)(hpe_lds + r * 68 + k4) =
                    make_float4(hv.x + pv.x, hv.y + pv.y, hv.z + pv.z, hv.w + pv.w);
            }
        }
        __syncthreads();
#pragma unroll 4
        for (int k = 0; k < 64; k++) {
            float wv[8];
            float4 wa = *(float4*)(w_lds + k * 128 + tc * 8);
            float4 wb = *(float4*)(w_lds + k * 128 + tc * 8 + 4);
            wv[0] = wa.x; wv[1] = wa.y; wv[2] = wa.z; wv[3] = wa.w;
            wv[4] = wb.x; wv[5] = wb.y; wv[6] = wb.z; wv[7] = wb.w;
#pragma unroll
            for (int i = 0; i < 2; i++) {
                float hv = hpe_lds[(tr * 2 + i) * 68 + k];
#pragma unroll
                for (int j = 0; j < 8; j++) acc[i][j] = fmaf(hv, wv[j], acc[i][j]);
            }
        }
        __syncthreads();
    }

    float a1v[8], a2v[8];
#pragma unroll
    for (int j = 0; j < 8; j++) { a1v[j] = a[tc * 8 + j]; a2v[j] = a[FDIM + tc * 8 + j]; }
#pragma unroll
    for (int i = 0; i < 2; i++) {
        int n = n0 + tr * 2 + i;
        float* dst = Wh + ((size_t)b * NN + n) * FDIM + tc * 8;
        *(float4*)dst = make_float4(acc[i][0], acc[i][1], acc[i][2], acc[i][3]);
        *(float4*)(dst + 4) = make_float4(acc[i][4], acc[i][5], acc[i][6], acc[i][7]);
        float p1 = 0.f, p2 = 0.f;
#pragma unroll
        for (int j = 0; j < 8; j++) {
            p1 = fmaf(acc[i][j], a1v[j], p1);
            p2 = fmaf(acc[i][j], a2v[j], p2);
        }
#pragma unroll
        for (int off = 1; off < 16; off <<= 1) {   // reduce across the 16 tc lanes
            p1 += __shfl_xor(p1, off, 64);
            p2 += __shfl_xor(p2, off, 64);
        }
        if (tc == 0) {
            s1[(size_t)b * NN + n] = p1;
            s2[(size_t)b * NN + n] = p2;
        }
    }
}

// ---------------- kernel 3: stream adj, row softmax, column-sum partials ---
// grid (128 chunks of 16 rows, 8 b) = 1024 blocks, 256 threads = 4 waves.
// launch_bounds(256,1): let the compiler SPEND registers. Explicit software
// pipeline: double-buffered row regs (cur/nxt) keep 8 loads always in
// flight; p[32] kept in regs (single exp); per-wave private LDS c-slices
// (no atomics). s2 in LDS. Entire grid resident (4 blocks/CU, 40KB LDS).
__global__ __launch_bounds__(256, 1) void k_attn(const float* __restrict__ adj,
                                                 const float* __restrict__ s1,
                                                 const float* __restrict__ s2,
                                                 float* __restrict__ c_part) {
    const int b = blockIdx.y;
    const int chunk = blockIdx.x;      // 16 rows per chunk
    const int t = threadIdx.x;
    const int wave = t >> 6;
    const int lane = t & 63;
    __shared__ float s2_lds[NN];       // 8 KB
    __shared__ float slice[4][NN];     // 32 KB, per-wave private

    const float* s2b = s2 + (size_t)b * NN;
#pragma unroll
    for (int q = 0; q < 2; q++) {
        int idx = t + q * 256;
        ((float4*)s2_lds)[idx] = ((const float4*)s2b)[idx];
    }
    // zero own slice (same lanes later RMW same addresses: no barrier needed)
#pragma unroll
    for (int kq = 0; kq < 8; kq++)
        *(float4*)&slice[wave][kq * 256 + lane * 4] = make_float4(0.f, 0.f, 0.f, 0.f);
    __syncthreads();                   // covers s2_lds visibility

    const int nbase = chunk * 16 + wave * 4;
    const float* adjb = adj + (size_t)b * NN * NN;
    const float* s1b = s1 + (size_t)b * NN;

    float4 cur[8], nxt[8];
    {
        const float4* rp = (const float4*)(adjb + (size_t)nbase * NN);
#pragma unroll
        for (int kq = 0; kq < 8; kq++) cur[kq] = rp[kq * 64 + lane];
    }

#pragma unroll
    for (int ri = 0; ri < 4; ri++) {
        const int n = nbase + ri;
        if (ri < 3) {                  // prefetch next row while computing
            const float4* rq = (const float4*)(adjb + (size_t)(n + 1) * NN);
#pragma unroll
            for (int kq = 0; kq < 8; kq++) nxt[kq] = rq[kq * 64 + lane];
        }
        const float s1n = s1b[n];
        float p[32];
        float z = 0.f;
#pragma unroll
        for (int kq = 0; kq < 8; kq++) {
            float4 av = cur[kq];
            float4 sv = ((const float4*)s2_lds)[kq * 64 + lane];
            float a4[4] = {av.x, av.y, av.z, av.w};
            float s4[4] = {sv.x, sv.y, sv.z, sv.w};
#pragma unroll
            for (int e = 0; e < 4; e++) {
                int j = kq * 4 + e;
                int m = kq * 256 + lane * 4 + e;
                float x = s1n + s4[e];
                float ev = fmaxf(x, 0.2f * x);           // LeakyReLU
                bool conn = (a4[e] > 0.f) || (m == n);   // forced diagonal
                float pe_ = conn ? __expf(ev) : 0.f;
                p[j] = pe_;
                z += pe_;
            }
        }
#pragma unroll
        for (int off = 32; off; off >>= 1) z += __shfl_xor(z, off, 64);
        const float rz = (n != 0) ? 1.f / z : 0.f;   // valid[:,0]=False
#pragma unroll
        for (int kq = 0; kq < 8; kq++) {
            float4 cv = *(float4*)&slice[wave][kq * 256 + lane * 4];
            cv.x += p[kq * 4 + 0] * rz;
            cv.y += p[kq * 4 + 1] * rz;
            cv.z += p[kq * 4 + 2] * rz;
            cv.w += p[kq * 4 + 3] * rz;
            *(float4*)&slice[wave][kq * 256 + lane * 4] = cv;
        }
        if (ri < 3) {
#pragma unroll
            for (int kq = 0; kq < 8; kq++) cur[kq] = nxt[kq];
        }
    }
    __syncthreads();

    // combine 4 wave slices -> block partial
    float* dst = c_part + ((size_t)b * 128 + chunk) * NN;
#pragma unroll
    for (int q = 0; q < 2; q++) {
        int idx = t + q * 256;   // float4 index 0..511
        float4 v0 = ((const float4*)slice[0])[idx];
        float4 v1 = ((const float4*)slice[1])[idx];
        float4 v2 = ((const float4*)slice[2])[idx];
        float4 v3 = ((const float4*)slice[3])[idx];
        ((float4*)dst)[idx] = make_float4(v0.x + v1.x + v2.x + v3.x,
                                          v0.y + v1.y + v2.y + v3.y,
                                          v0.z + v1.z + v2.z + v3.z,
                                          v0.w + v1.w + v2.w + v3.w);
    }
}

// ---------------- kernel 4: reduce c_part + g_part = c^T * Wh partials -----
// grid (32 m-chunks of 64, 8 b), 256 threads
__global__ __launch_bounds__(256) void k_gpre(const float* __restrict__ Wh,
                                              const float* __restrict__ c_part,
                                              float* __restrict__ g_part) {
    const int b = blockIdx.y;
    const int mc = blockIdx.x;
    const int m0 = mc * 64;
    const int t = threadIdx.x;
    __shared__ float red[256];
    __shared__ float c_lds[64];

    // phase 1: c[b][m0+mi] = sum over 128 chunk-partials (4 waves x 32 each)
    {
        const int mi = t & 63;
        const int w = t >> 6;
        const float* cp = c_part + (size_t)b * 128 * NN + m0 + mi;
        float s = 0.f;
#pragma unroll 8
        for (int j = 0; j < 32; j++) s += cp[(size_t)(w * 32 + j) * NN];
        red[w * 64 + mi] = s;
    }
    __syncthreads();
    if (t < 64) c_lds[t] = red[t] + red[t + 64] + red[t + 128] + red[t + 192];
    __syncthreads();

    // phase 2: partial g over this m-chunk
    const int o = t & 127;
    const int mh = t >> 7;              // 0/1
    float acc = 0.f;
    const float* whb = Wh + ((size_t)b * NN + m0 + mh * 32) * FDIM;
#pragma unroll 4
    for (int mm = 0; mm < 32; mm++)
        acc = fmaf(c_lds[mh * 32 + mm], whb[mm * FDIM + o], acc);
    g_part[((size_t)(mc * 2 + mh)) * (BATCH * FDIM) + b * FDIM + o] = acc;
}

// ---------------- kernel 5: out = elu( (sum of 64 partials) / 2047 ) -------
__global__ void k_elu(const float* __restrict__ g_part, float* __restrict__ out) {
    int i = blockIdx.x * 256 + threadIdx.x;    // 0..1023 = b*128+o
    if (i < BATCH * FDIM) {
        float s = 0.f;
#pragma unroll 8
        for (int p = 0; p < 64; p++) s += g_part[p * (BATCH * FDIM) + i];
        float g = s * (1.0f / 2047.0f);
        out[i] = g > 0.f ? g : expm1f(g);
    }
}

extern "C" void kernel_launch(void* const* d_in, const int* in_sizes, int n_in,
                              void* d_out, int out_size, void* d_ws, size_t ws_size,
                              hipStream_t stream) {
    (void)in_sizes; (void)n_in; (void)out_size; (void)ws_size;
    const float* h   = (const float*)d_in[0];
    const float* adj = (const float*)d_in[1];
    const float* W   = (const float*)d_in[2];
    const float* a   = (const float*)d_in[3];
    float* out = (float*)d_out;

    char* ws = (char*)d_ws;
    float* Wh     = (float*)ws;                                   // 8*2048*128
    float* pe     = Wh + (size_t)BATCH * NN * FDIM;               // 2048*128
    float* s1     = pe + (size_t)NN * FDIM;                       // 8*2048
    float* s2     = s1 + (size_t)BATCH * NN;                      // 8*2048
    float* c_part = s2 + (size_t)BATCH * NN;                      // 8*128*2048
    float* g_part = c_part + (size_t)BATCH * 128 * NN;            // 64*8*128

    hipLaunchKernelGGL(k_pe, dim3(NN * FDIM / 256), dim3(256), 0, stream, pe);
    hipLaunchKernelGGL(k_wh, dim3(NN / 64, BATCH), dim3(512), 0, stream,
                       h, pe, W, a, Wh, s1, s2);
    hipLaunchKernelGGL(k_attn, dim3(NN / 16, BATCH), dim3(256), 0, stream,
                       adj, s1, s2, c_part);
    hipLaunchKernelGGL(k_gpre, dim3(NN / 64, BATCH), dim3(256), 0, stream,
                       Wh, c_part, g_part);
    hipLaunchKernelGGL(k_elu, dim3(4), dim3(256), 0, stream, g_part, out);
}